// Round 17
// baseline (4826.667 us; speedup 1.0000x reference)
//
#include <hip/hip_runtime.h>
#include <stdint.h>

#define Bsz   4096
#define STEPS 127
#define NTH   512
#define NB    2          // batches per block, phase-staggered software pipeline

typedef float    f4v __attribute__((ext_vector_type(4)));
typedef float    f2v __attribute__((ext_vector_type(2)));
typedef uint32_t u4v __attribute__((ext_vector_type(4)));
typedef _Float16 h2v __attribute__((ext_vector_type(2)));
typedef __fp16   g2v __attribute__((ext_vector_type(2)));

#define K2E  1.4426950408889634f
#define K2E2 2.8853900817779268f

extern "C" __device__ _Float16 __ocml_exp2_f16(_Float16);

__device__ __forceinline__ float rcp_f(float x) { return __builtin_amdgcn_rcpf(x); }
__device__ __forceinline__ float exp2_f(float x) {
#if __has_builtin(__builtin_amdgcn_exp2f)
    return __builtin_amdgcn_exp2f(x);
#else
    return exp2f(x);
#endif
}
__device__ __forceinline__ _Float16 rcp_h(_Float16 x) {
#if __has_builtin(__builtin_amdgcn_rcph)
    return __builtin_amdgcn_rcph(x);
#else
    return (_Float16)rcp_f((float)x);
#endif
}
__device__ __forceinline__ _Float16 exp2_h(_Float16 x) { return __ocml_exp2_f16(x); }
__device__ __forceinline__ float sig_f(float x)  { return rcp_f(1.f + exp2_f(-K2E * x)); }
__device__ __forceinline__ float tanh_f(float x) { return 1.f - 2.f * rcp_f(1.f + exp2_f(K2E2 * x)); }
__device__ __forceinline__ uint32_t pkh2(float a, float b) {
    union { uint32_t u; g2v h; } v;
    v.h = __builtin_amdgcn_cvt_pkrtz(a, b);
    return v.u;
}
__device__ __forceinline__ h2v uh(uint32_t u) {
    union { uint32_t u; h2v h; } v; v.u = u; return v.h;
}
__device__ __forceinline__ float dot2(uint32_t a, uint32_t b, float c) {
    union { uint32_t u; h2v h; } x, y;
    x.u = a; y.u = b;
#if __has_builtin(__builtin_amdgcn_fdot2)
    return __builtin_amdgcn_fdot2(x.h, y.h, c, false);
#else
    return c + (float)x.h[0] * (float)y.h[0] + (float)x.h[1] * (float)y.h[1];
#endif
}

// ---- DPP cross-lane (VALU pipe) ----
template<int CTRL, int RM, int BM>
__device__ __forceinline__ float dpp_add(float v) {
    union { float f; int i; } s, t;
    s.f = v;
    t.i = __builtin_amdgcn_update_dpp(0, s.i, CTRL, RM, BM, true);
    return v + t.f;
}
template<int CTRL>
__device__ __forceinline__ float dpp_mov(float v) {
    union { float f; int i; } s, t;
    s.f = v;
    t.i = __builtin_amdgcn_mov_dpp(s.i, CTRL, 0xf, 0xf, true);
    return t.f;
}
__device__ __forceinline__ float rd63(float v) {
    union { float f; int i; } s; s.f = v;
    union { int i; float f; } r; r.i = __builtin_amdgcn_readlane(s.i, 63);
    return r.f;
}
__device__ __forceinline__ float qsum(float v) {
    v = dpp_add<0xB1, 0xf, 0xf>(v);   // quad_perm xor1
    v = dpp_add<0x4E, 0xf, 0xf>(v);   // quad_perm xor2
    return v;
}
__device__ __forceinline__ float wsum(float v) {
    v = dpp_add<0x111, 0xf, 0xf>(v);  // row_shr:1
    v = dpp_add<0x112, 0xf, 0xf>(v);  // row_shr:2
    v = dpp_add<0x114, 0xf, 0xe>(v);  // row_shr:4
    v = dpp_add<0x118, 0xf, 0xc>(v);  // row_shr:8
    v = dpp_add<0x142, 0xa, 0xf>(v);  // row_bcast:15
    v = dpp_add<0x143, 0xc, 0xf>(v);  // row_bcast:31
    return rd63(v);
}

// R17 = R16 (best: 4.50ms) + R13's packed-fp16 phase B (prescaled EPT,
// packed hc2, v_exp_f16/v_rcp_f16): ~20% fewer B cycles. R13 measured this
// neutral pre-stagger (stall-bound); now issue-bound (VALUBusy 70%) it should
// translate. fp16 overflow saturates correctly (exp2->inf->rcp->0).
__global__ __launch_bounds__(NTH, 1)
void dec_kernel(const float* __restrict__ X,    // (B,128,128)
                const float* __restrict__ yh,   // (B,127,1)
                const float* __restrict__ W1,   // (128,384)
                const float* __restrict__ b1,   // (128)
                const float* __restrict__ W2,   // (1,128)
                const float* __restrict__ b2u,  // (1) softmax-invariant
                const float* __restrict__ Wih,  // (512,1)
                const float* __restrict__ Whh,  // (512,128)
                const float* __restrict__ bih,  // (512)
                const float* __restrict__ bhh,  // (512)
                const float* __restrict__ fcW,  // (1,129)
                const float* __restrict__ fcb,  // (1)
                const float* __restrict__ Wff,  // (1,256)
                const float* __restrict__ bff,  // (1)
                float* __restrict__ out)        // (B,1)
{
    const int tid  = threadIdx.x;
    const int lane = tid & 63;

    __shared__ __align__(16) uint32_t EPT_pk[NB][128 * 68]; // K2E2*enc_proj fp16 pairs, t-major
    __shared__ __align__(16) float    Xt[8][132];           // setup staging (shared)
    __shared__ __align__(16) uint32_t st2[NB][2][144];      // h2 pairs concat(h,c)
    __shared__ __align__(16) float    c32[NB][2][128];
    __shared__ __align__(16) float    h32[NB][128];
    __shared__ __align__(16) float    p_s[NB][128];         // exp2(K2E*e), PAIR layout
    __shared__ __align__(16) uint32_t hc2pk[NB][68];        // K2E2*(hc+b1) fp16 pairs
    __shared__ __align__(16) uint32_t w2pk[68];             // -2*w2 fp16 pairs
    __shared__ __align__(16) float    y_s[NB][STEPS + 1];   // prescaled fcwy*y + fcb
    __shared__ __align__(16) float    XFa[NB][128];         // fcW-proj, PAIR layout
    __shared__ __align__(16) float    XGa[NB][128];         // Wff-proj, PAIR layout

    const float* Xb0 = X + (size_t)blockIdx.x * NB * (128 * 128);

    for (int i = tid; i < NB * 2 * 144; i += NTH) ((uint32_t*)st2)[i] = 0u;
    if (tid < 128) { c32[0][0][tid] = 0.f; c32[1][0][tid] = 0.f; }
    if (tid < STEPS) {
        y_s[0][tid] = fcW[128] * yh[(size_t)(blockIdx.x * NB + 0) * STEPS + tid] + fcb[0];
        y_s[1][tid] = fcW[128] * yh[(size_t)(blockIdx.x * NB + 1) * STEPS + tid] + fcb[0];
    }
    if (tid < 64) w2pk[tid] = pkh2(-2.f * W2[2 * tid], -2.f * W2[2 * tid + 1]);

    const int jA = tid >> 2;   // 0..127
    const int qA = tid & 3;    // 4 threads per j

    // ---- XF/XG per batch (ctx eliminated); pair layout [ (j&63)*2 + (j>>6) ] ----
    #pragma unroll
    for (int bb = 0; bb < NB; ++bb) {
        const float* Xb = Xb0 + bb * (128 * 128);
        float aF = 0.f, aG = 0.f;
        #pragma unroll
        for (int u = 0; u < 8; ++u) {
            f4v xv = *(const f4v*)(Xb + jA * 128 + qA * 32 + 4 * u);
            f4v fv = *(const f4v*)(fcW + qA * 32 + 4 * u);
            f4v gv = *(const f4v*)(Wff + 128 + qA * 32 + 4 * u);
            aF += xv[0]*fv[0] + xv[1]*fv[1] + xv[2]*fv[2] + xv[3]*fv[3];
            aG += xv[0]*gv[0] + xv[1]*gv[1] + xv[2]*gv[2] + xv[3]*gv[3];
        }
        aF = qsum(aF);
        aG = qsum(aG);
        int sl = (jA & 63) * 2 + (jA >> 6);
        if (qA == 0) { XFa[bb][sl] = aF; XGa[bb][sl] = aG; }
    }

    // ---- enc_proj per batch (fp32 math; PRESCALED K2E2, fp16-pair t-major) ----
    {
        float w1e[32];
        #pragma unroll
        for (int u = 0; u < 8; ++u) {
            f4v w = *(const f4v*)(W1 + jA * 384 + 256 + qA * 32 + 4 * u);
            w1e[4*u] = w[0]; w1e[4*u+1] = w[1]; w1e[4*u+2] = w[2]; w1e[4*u+3] = w[3];
        }
        for (int bb = 0; bb < NB; ++bb) {
            const float* Xb = Xb0 + bb * (128 * 128);
            for (int tile = 0; tile < 16; ++tile) {
                __syncthreads();
                if (tid < 256) {   // stage 8 rows; slot swizzle for broadcast reads
                    int row = tid >> 5, c4 = tid & 31;
                    int p = (c4 & 7) * 4 + (c4 >> 3);
                    *(f4v*)&Xt[row][p * 4] = *(const f4v*)(Xb + (tile * 8 + row) * 128 + c4 * 4);
                }
                __syncthreads();
                #pragma unroll
                for (int tl = 0; tl < 8; ++tl) {
                    float acc = 0.f;
                    #pragma unroll
                    for (int u = 0; u < 8; ++u) {
                        f4v xv = *(const f4v*)&Xt[tl][(u * 4 + qA) * 4];
                        acc += xv[0]*w1e[4*u] + xv[1]*w1e[4*u+1]
                             + xv[2]*w1e[4*u+2] + xv[3]*w1e[4*u+3];
                    }
                    acc = K2E2 * qsum(acc);
                    float accp = __shfl_xor(acc, 4);          // partner j (setup-only)
                    if ((tid & 7) == 0)
                        EPT_pk[bb][(tile * 8 + tl) * 68 + (tid >> 3)] = pkh2(acc, accp);
                }
            }
        }
    }

    // ---- persistent weights (fp16-pair packed, shared across batches) ----
    uint32_t w1pk[32];
    #pragma unroll
    for (int m = 0; m < 16; ++m) {
        f4v a = *(const f4v*)(W1 + jA * 384 + qA * 64 + 4 * m);
        w1pk[2*m]   = pkh2(a[0], a[1]);
        w1pk[2*m+1] = pkh2(a[2], a[3]);
    }
    const int jD = tid >> 2;               // cell
    const int r  = (tid & 3) * 128 + jD;   // gate row (quad lane q = gate q)
    uint32_t whh[64];
    #pragma unroll
    for (int m = 0; m < 32; ++m) {
        f4v w = *(const f4v*)(Whh + (size_t)r * 128 + 4 * m);
        whh[2*m]   = pkh2(w[0], w[1]);
        whh[2*m+1] = pkh2(w[2], w[3]);
    }
    const float wihv = Wih[r];
    const float bgv  = bih[r] + bhh[r];
    const float b1s  = K2E2 * b1[jA];
    float ytg0 = 0.f, ytg1 = 0.f;
    __syncthreads();

    // ---- phase bodies (b is a literal at every call site -> fully folded) ----
    auto PH_A = [&](int b, int s) {
        const int cur = s & 1;
        float a0 = 0.f, a1 = 0.f;
        const uint32_t* sb = &st2[b][cur][qA * 36];
        #pragma unroll
        for (int u = 0; u < 8; ++u) {
            u4v sv = *(const u4v*)(sb + 4 * u);
            a0 = dot2(sv[0], w1pk[4*u],   a0);
            a1 = dot2(sv[1], w1pk[4*u+1], a1);
            a0 = dot2(sv[2], w1pk[4*u+2], a0);
            a1 = dot2(sv[3], w1pk[4*u+3], a1);
        }
        float val = fmaf(K2E2, qsum(a0 + a1), b1s);   // valid on all quad lanes
        float valp = __shfl_xor(val, 4);              // partner j's value
        if ((tid & 7) == 0) hc2pk[b][tid >> 3] = pkh2(val, valp);
    };

    auto PH_B = [&](int b) {
        const int tt = tid >> 2, q = tid & 3;     // 4 lanes/t, 32 h each
        const uint32_t* er = &EPT_pk[b][tt * 68 + q * 16];
        const uint32_t* hr = &hc2pk[b][q * 16];
        const uint32_t* wr = &w2pk[q * 16];
        _Float16 accL = (_Float16)0.f, accH = (_Float16)0.f;
        const _Float16 one = (_Float16)1.f;
        #pragma unroll
        for (int u = 0; u < 4; ++u) {
            u4v ev = *(const u4v*)(er + 4 * u);
            u4v hv = *(const u4v*)(hr + 4 * u);   // broadcast
            u4v wv = *(const u4v*)(wr + 4 * u);   // broadcast
            #pragma unroll
            for (int m = 0; m < 4; ++m) {
                h2v z  = uh(ev[m]) + uh(hv[m]);   // v_pk_add_f16
                h2v w2 = uh(wv[m]);
                _Float16 p0 = exp2_h(z[0]);       // overflow->inf->rcp->0 (saturates)
                _Float16 p1 = exp2_h(z[1]);
                accL += w2[0] * rcp_h(one + p0);
                accH += w2[1] * rcp_h(one + p1);
            }
        }
        float acc = qsum((float)accL + (float)accH);
        float pt = exp2_f(K2E * acc);             // no max pass: |e| bounded ~10
        if (q == 0) p_s[b][(tt & 63) * 2 + (tt >> 6)] = pt;   // pair layout
    };

    auto PH_C = [&](int b, int s, float& ytg_ref) {
        const int cur = s & 1;
        // D-dot (independent ILP filler under the serial wsum chains)
        float d0 = 0.f, d1 = 0.f, d2 = 0.f, d3 = 0.f;
        const uint32_t* hb = &st2[b][cur][0];
        #pragma unroll
        for (int m = 0; m < 8; ++m) {
            u4v sv = *(const u4v*)(hb + 4 * m);
            d0 = dot2(sv[0], whh[4*m],   d0);
            d1 = dot2(sv[1], whh[4*m+1], d1);
            d2 = dot2(sv[2], whh[4*m+2], d2);
            d3 = dot2(sv[3], whh[4*m+3], d3);
        }
        #pragma unroll
        for (int m = 0; m < 8; ++m) {
            u4v sv = *(const u4v*)(hb + 36 + 4 * m);
            d0 = dot2(sv[0], whh[32 + 4*m],   d0);
            d1 = dot2(sv[1], whh[32 + 4*m+1], d1);
            d2 = dot2(sv[2], whh[32 + 4*m+2], d2);
            d3 = dot2(sv[3], whh[32 + 4*m+3], d3);
        }
        float gdot = (d0 + d1) + (d2 + d3);
        // softmax reduce from p_s (pair layout: 3 b64 reads)
        f2v pv = *(const f2v*)&p_s[b][2 * lane];
        f2v xf = *(const f2v*)&XFa[b][2 * lane];
        f2v xg = *(const f2v*)&XGa[b][2 * lane];
        float sp = wsum(pv[0] + pv[1]);
        float sf = wsum(pv[0] * xf[0] + pv[1] * xf[1]);
        float sg = wsum(pv[0] * xg[0] + pv[1] * xg[1]);
        float inv = rcp_f(sp);
        float ytc = sf * inv;
        ytg_ref   = sg * inv;
        // gate finish + LSTM update
        float g  = gdot + fmaf(wihv, ytc + y_s[b][s], bgv);
        float gb = dpp_mov<0xB1>(g);    // at quad lane 0: g=i, gb=f, gc=g, gd=o
        float gc = dpp_mov<0x4E>(g);
        float gd = dpp_mov<0x4E>(gb);
        if ((tid & 3) == 0) {
            float co = c32[b][cur][jD];
            float cn = sig_f(gb) * co + sig_f(g) * tanh_f(gc);
            float hn = sig_f(gd) * tanh_f(cn);
            c32[b][cur ^ 1][jD] = cn;
            h32[b][jD] = hn;
            float hp = __shfl_xor(hn, 4);
            float cp = __shfl_xor(cn, 4);
            if ((tid & 7) == 0) {
                int m0 = tid >> 3;
                int sl = m0 + 4 * (m0 >> 5);
                st2[b][cur ^ 1][sl]      = pkh2(hn, hp);
                st2[b][cur ^ 1][72 + sl] = pkh2(cn, cp);
            }
        }
    };

    // ================= staggered scan: 3 regions advance BOTH batches 1 step ===
    PH_A(0, 0);
    __syncthreads();
    PH_B(0);  PH_A(1, 0);
    __syncthreads();

    for (int s = 0; s < STEPS - 1; ++s) {
        PH_C(0, s, ytg0);      PH_B(1);
        __syncthreads();
        PH_A(0, s + 1);        PH_C(1, s, ytg1);
        __syncthreads();
        PH_B(0);               PH_A(1, s + 1);
        __syncthreads();
    }
    PH_C(0, STEPS - 1, ytg0);  PH_B(1);
    __syncthreads();
    PH_C(1, STEPS - 1, ytg1);
    __syncthreads();

    // ---- out = h·Wff[0:128] + β_last·XG + bff, per batch ----
    if (tid < 64) {
        float v0 = h32[0][lane] * Wff[lane] + h32[0][lane + 64] * Wff[lane + 64];
        v0 = wsum(v0);
        float v1 = h32[1][lane] * Wff[lane] + h32[1][lane + 64] * Wff[lane + 64];
        v1 = wsum(v1);
        if (lane == 0) {
            out[blockIdx.x * NB + 0] = v0 + ytg0 + bff[0];
            out[blockIdx.x * NB + 1] = v1 + ytg1 + bff[0];
        }
    }
}

extern "C" void kernel_launch(void* const* d_in, const int* in_sizes, int n_in,
                              void* d_out, int out_size, void* d_ws, size_t ws_size,
                              hipStream_t stream) {
    dec_kernel<<<Bsz / NB, NTH, 0, stream>>>(
        (const float*)d_in[0],  (const float*)d_in[1],  (const float*)d_in[2],
        (const float*)d_in[3],  (const float*)d_in[4],  (const float*)d_in[5],
        (const float*)d_in[6],  (const float*)d_in[7],  (const float*)d_in[8],
        (const float*)d_in[9],  (const float*)d_in[10], (const float*)d_in[11],
        (const float*)d_in[12], (const float*)d_in[13], (float*)d_out);
}

// Round 18
// 4493.672 us; speedup vs baseline: 1.0741x; 1.0741x over previous
//
#include <hip/hip_runtime.h>
#include <stdint.h>

#define Bsz   4096
#define STEPS 127
#define NTH   512
#define NB    2          // batches per block, phase-staggered software pipeline

typedef float    f4v __attribute__((ext_vector_type(4)));
typedef float    f2v __attribute__((ext_vector_type(2)));
typedef uint32_t u4v __attribute__((ext_vector_type(4)));
typedef _Float16 h2v __attribute__((ext_vector_type(2)));
typedef __fp16   g2v __attribute__((ext_vector_type(2)));

#define K2E  1.4426950408889634f
#define K2E2 2.8853900817779268f

__device__ __forceinline__ float rcp_f(float x) { return __builtin_amdgcn_rcpf(x); }
__device__ __forceinline__ float exp2_f(float x) {
#if __has_builtin(__builtin_amdgcn_exp2f)
    return __builtin_amdgcn_exp2f(x);
#else
    return exp2f(x);
#endif
}
__device__ __forceinline__ float sig_f(float x)  { return rcp_f(1.f + exp2_f(-K2E * x)); }
__device__ __forceinline__ float tanh_f(float x) { return 1.f - 2.f * rcp_f(1.f + exp2_f(K2E2 * x)); }
__device__ __forceinline__ uint32_t pkh2(float a, float b) {
    union { uint32_t u; g2v h; } v;
    v.h = __builtin_amdgcn_cvt_pkrtz(a, b);
    return v.u;
}
__device__ __forceinline__ float h2lo(uint32_t p) {
    union { uint32_t u; h2v h; } v; v.u = p; return (float)v.h[0];
}
__device__ __forceinline__ float h2hi(uint32_t p) {
    union { uint32_t u; h2v h; } v; v.u = p; return (float)v.h[1];
}
__device__ __forceinline__ float dot2(uint32_t a, uint32_t b, float c) {
    union { uint32_t u; h2v h; } x, y;
    x.u = a; y.u = b;
#if __has_builtin(__builtin_amdgcn_fdot2)
    return __builtin_amdgcn_fdot2(x.h, y.h, c, false);
#else
    return c + (float)x.h[0] * (float)y.h[0] + (float)x.h[1] * (float)y.h[1];
#endif
}

// ---- DPP cross-lane (VALU pipe) ----
template<int CTRL, int RM, int BM>
__device__ __forceinline__ float dpp_add(float v) {
    union { float f; int i; } s, t;
    s.f = v;
    t.i = __builtin_amdgcn_update_dpp(0, s.i, CTRL, RM, BM, true);
    return v + t.f;
}
template<int CTRL>
__device__ __forceinline__ float dpp_mov(float v) {
    union { float f; int i; } s, t;
    s.f = v;
    t.i = __builtin_amdgcn_mov_dpp(s.i, CTRL, 0xf, 0xf, true);
    return t.f;
}
__device__ __forceinline__ float rd63(float v) {
    union { float f; int i; } s; s.f = v;
    union { int i; float f; } r; r.i = __builtin_amdgcn_readlane(s.i, 63);
    return r.f;
}
__device__ __forceinline__ float qsum(float v) {
    v = dpp_add<0xB1, 0xf, 0xf>(v);   // quad_perm xor1
    v = dpp_add<0x4E, 0xf, 0xf>(v);   // quad_perm xor2
    return v;
}
__device__ __forceinline__ float wsum(float v) {
    v = dpp_add<0x111, 0xf, 0xf>(v);  // row_shr:1
    v = dpp_add<0x112, 0xf, 0xf>(v);  // row_shr:2
    v = dpp_add<0x114, 0xf, 0xe>(v);  // row_shr:4
    v = dpp_add<0x118, 0xf, 0xc>(v);  // row_shr:8
    v = dpp_add<0x142, 0xa, 0xf>(v);  // row_bcast:15
    v = dpp_add<0x143, 0xc, 0xf>(v);  // row_bcast:31
    return rd63(v);
}

// R18 = R16 verbatim (best measured: 4.50ms). R17's packed-fp16 B regressed
// (ocml exp2_f16 expands multi-inst); reverted. Structure pinned by measured
// platform walls: 8 waves/CU @512thr VGPR>64; 64-VGPR cap @1024thr; ~104-reg
// weight floor; 2-deep stagger at 128-VGPR ceiling.
__global__ __launch_bounds__(NTH, 1)
void dec_kernel(const float* __restrict__ X,    // (B,128,128)
                const float* __restrict__ yh,   // (B,127,1)
                const float* __restrict__ W1,   // (128,384)
                const float* __restrict__ b1,   // (128)
                const float* __restrict__ W2,   // (1,128)
                const float* __restrict__ b2u,  // (1) softmax-invariant
                const float* __restrict__ Wih,  // (512,1)
                const float* __restrict__ Whh,  // (512,128)
                const float* __restrict__ bih,  // (512)
                const float* __restrict__ bhh,  // (512)
                const float* __restrict__ fcW,  // (1,129)
                const float* __restrict__ fcb,  // (1)
                const float* __restrict__ Wff,  // (1,256)
                const float* __restrict__ bff,  // (1)
                float* __restrict__ out)        // (B,1)
{
    const int tid  = threadIdx.x;
    const int lane = tid & 63;

    __shared__ __align__(16) uint32_t EPT_pk[NB][128 * 68]; // enc_proj fp16 pairs, t-major
    __shared__ __align__(16) float    Xt[8][132];           // setup staging (shared)
    __shared__ __align__(16) uint32_t st2[NB][2][144];      // h2 pairs concat(h,c)
    __shared__ __align__(16) float    c32[NB][2][128];
    __shared__ __align__(16) float    h32[NB][128];
    __shared__ __align__(16) float    p_s[NB][128];         // exp2(K2E*e), PAIR layout
    __shared__ __align__(16) float    hc2c[NB][4][36];      // K2E2*(hc+b1), chunk-padded
    __shared__ __align__(16) float    w2m[4][36];           // -2*w2
    __shared__ __align__(16) float    y_s[NB][STEPS + 1];   // prescaled fcwy*y + fcb
    __shared__ __align__(16) float    XFa[NB][128];         // fcW-proj, PAIR layout
    __shared__ __align__(16) float    XGa[NB][128];         // Wff-proj, PAIR layout

    const float* Xb0 = X + (size_t)blockIdx.x * NB * (128 * 128);

    for (int i = tid; i < NB * 2 * 144; i += NTH) ((uint32_t*)st2)[i] = 0u;
    if (tid < 128) { c32[0][0][tid] = 0.f; c32[1][0][tid] = 0.f; }
    if (tid < STEPS) {
        y_s[0][tid] = fcW[128] * yh[(size_t)(blockIdx.x * NB + 0) * STEPS + tid] + fcb[0];
        y_s[1][tid] = fcW[128] * yh[(size_t)(blockIdx.x * NB + 1) * STEPS + tid] + fcb[0];
    }
    if (tid < 128) w2m[tid >> 5][tid & 31] = -2.f * W2[tid];

    const int jA = tid >> 2;   // 0..127
    const int qA = tid & 3;    // 4 threads per j

    // ---- XF/XG per batch (ctx eliminated); pair layout [ (j&63)*2 + (j>>6) ] ----
    #pragma unroll
    for (int bb = 0; bb < NB; ++bb) {
        const float* Xb = Xb0 + bb * (128 * 128);
        float aF = 0.f, aG = 0.f;
        #pragma unroll
        for (int u = 0; u < 8; ++u) {
            f4v xv = *(const f4v*)(Xb + jA * 128 + qA * 32 + 4 * u);
            f4v fv = *(const f4v*)(fcW + qA * 32 + 4 * u);
            f4v gv = *(const f4v*)(Wff + 128 + qA * 32 + 4 * u);
            aF += xv[0]*fv[0] + xv[1]*fv[1] + xv[2]*fv[2] + xv[3]*fv[3];
            aG += xv[0]*gv[0] + xv[1]*gv[1] + xv[2]*gv[2] + xv[3]*gv[3];
        }
        aF = qsum(aF);
        aG = qsum(aG);
        int sl = (jA & 63) * 2 + (jA >> 6);
        if (qA == 0) { XFa[bb][sl] = aF; XGa[bb][sl] = aG; }
    }

    // ---- enc_proj per batch (fp32 math, fp16-pair t-major store) ----
    {
        float w1e[32];
        #pragma unroll
        for (int u = 0; u < 8; ++u) {
            f4v w = *(const f4v*)(W1 + jA * 384 + 256 + qA * 32 + 4 * u);
            w1e[4*u] = w[0]; w1e[4*u+1] = w[1]; w1e[4*u+2] = w[2]; w1e[4*u+3] = w[3];
        }
        for (int bb = 0; bb < NB; ++bb) {
            const float* Xb = Xb0 + bb * (128 * 128);
            for (int tile = 0; tile < 16; ++tile) {
                __syncthreads();
                if (tid < 256) {   // stage 8 rows; slot swizzle for broadcast reads
                    int row = tid >> 5, c4 = tid & 31;
                    int p = (c4 & 7) * 4 + (c4 >> 3);
                    *(f4v*)&Xt[row][p * 4] = *(const f4v*)(Xb + (tile * 8 + row) * 128 + c4 * 4);
                }
                __syncthreads();
                #pragma unroll
                for (int tl = 0; tl < 8; ++tl) {
                    float acc = 0.f;
                    #pragma unroll
                    for (int u = 0; u < 8; ++u) {
                        f4v xv = *(const f4v*)&Xt[tl][(u * 4 + qA) * 4];
                        acc += xv[0]*w1e[4*u] + xv[1]*w1e[4*u+1]
                             + xv[2]*w1e[4*u+2] + xv[3]*w1e[4*u+3];
                    }
                    acc = qsum(acc);
                    float accp = __shfl_xor(acc, 4);          // partner j (setup-only)
                    if ((tid & 7) == 0)
                        EPT_pk[bb][(tile * 8 + tl) * 68 + (tid >> 3)] = pkh2(acc, accp);
                }
            }
        }
    }

    // ---- persistent weights (fp16-pair packed, shared across batches) ----
    uint32_t w1pk[32];
    #pragma unroll
    for (int m = 0; m < 16; ++m) {
        f4v a = *(const f4v*)(W1 + jA * 384 + qA * 64 + 4 * m);
        w1pk[2*m]   = pkh2(a[0], a[1]);
        w1pk[2*m+1] = pkh2(a[2], a[3]);
    }
    const int jD = tid >> 2;               // cell
    const int r  = (tid & 3) * 128 + jD;   // gate row (quad lane q = gate q)
    uint32_t whh[64];
    #pragma unroll
    for (int m = 0; m < 32; ++m) {
        f4v w = *(const f4v*)(Whh + (size_t)r * 128 + 4 * m);
        whh[2*m]   = pkh2(w[0], w[1]);
        whh[2*m+1] = pkh2(w[2], w[3]);
    }
    const float wihv = Wih[r];
    const float bgv  = bih[r] + bhh[r];
    const float b1s  = K2E2 * b1[jA];
    float ytg0 = 0.f, ytg1 = 0.f;
    __syncthreads();

    // ---- phase bodies (b is a literal at every call site -> fully folded) ----
    auto PH_A = [&](int b, int s) {
        const int cur = s & 1;
        float a0 = 0.f, a1 = 0.f;
        const uint32_t* sb = &st2[b][cur][qA * 36];
        #pragma unroll
        for (int u = 0; u < 8; ++u) {
            u4v sv = *(const u4v*)(sb + 4 * u);
            a0 = dot2(sv[0], w1pk[4*u],   a0);
            a1 = dot2(sv[1], w1pk[4*u+1], a1);
            a0 = dot2(sv[2], w1pk[4*u+2], a0);
            a1 = dot2(sv[3], w1pk[4*u+3], a1);
        }
        float acc = qsum(a0 + a1);
        if (qA == 0) hc2c[b][jA >> 5][jA & 31] = fmaf(K2E2, acc, b1s);
    };

    auto PH_B = [&](int b) {
        const int tt = tid >> 2, q = tid & 3;     // 4 lanes/t, 32 h each
        const uint32_t* er = &EPT_pk[b][tt * 68 + q * 16];
        u4v ee0 = *(const u4v*)(er);
        u4v ee1 = *(const u4v*)(er + 4);
        u4v ee2 = *(const u4v*)(er + 8);
        u4v ee3 = *(const u4v*)(er + 12);
        float acc = 0.f;
        #pragma unroll
        for (int u = 0; u < 4; ++u) {
            u4v ev = (u == 0) ? ee0 : (u == 1) ? ee1 : (u == 2) ? ee2 : ee3;
            f4v hcv = *(const f4v*)&hc2c[b][q][8 * u];
            f4v hcw = *(const f4v*)&hc2c[b][q][8 * u + 4];
            f4v wv  = *(const f4v*)&w2m[q][8 * u];
            f4v wvw = *(const f4v*)&w2m[q][8 * u + 4];
            #pragma unroll
            for (int m = 0; m < 4; ++m) {
                uint32_t ep = ev[m];
                float hl = (m < 2) ? hcv[2*m]   : hcw[2*m-4];
                float hh = (m < 2) ? hcv[2*m+1] : hcw[2*m-3];
                float wl = (m < 2) ? wv[2*m]    : wvw[2*m-4];
                float wh = (m < 2) ? wv[2*m+1]  : wvw[2*m-3];
                float z0 = exp2_f(fmaf(h2lo(ep), K2E2, hl));
                float z1 = exp2_f(fmaf(h2hi(ep), K2E2, hh));
                acc = fmaf(wl, rcp_f(1.f + z0), acc);
                acc = fmaf(wh, rcp_f(1.f + z1), acc);
            }
        }
        acc = qsum(acc);
        float pt = exp2_f(K2E * acc);             // no max pass: |e| bounded ~10
        if (q == 0) p_s[b][(tt & 63) * 2 + (tt >> 6)] = pt;   // pair layout
    };

    auto PH_C = [&](int b, int s, float& ytg_ref) {
        const int cur = s & 1;
        // D-dot (independent ILP filler under the serial wsum chains)
        float d0 = 0.f, d1 = 0.f, d2 = 0.f, d3 = 0.f;
        const uint32_t* hb = &st2[b][cur][0];
        #pragma unroll
        for (int m = 0; m < 8; ++m) {
            u4v sv = *(const u4v*)(hb + 4 * m);
            d0 = dot2(sv[0], whh[4*m],   d0);
            d1 = dot2(sv[1], whh[4*m+1], d1);
            d2 = dot2(sv[2], whh[4*m+2], d2);
            d3 = dot2(sv[3], whh[4*m+3], d3);
        }
        #pragma unroll
        for (int m = 0; m < 8; ++m) {
            u4v sv = *(const u4v*)(hb + 36 + 4 * m);
            d0 = dot2(sv[0], whh[32 + 4*m],   d0);
            d1 = dot2(sv[1], whh[32 + 4*m+1], d1);
            d2 = dot2(sv[2], whh[32 + 4*m+2], d2);
            d3 = dot2(sv[3], whh[32 + 4*m+3], d3);
        }
        float gdot = (d0 + d1) + (d2 + d3);
        // softmax reduce from p_s (pair layout: 3 b64 reads)
        f2v pv = *(const f2v*)&p_s[b][2 * lane];
        f2v xf = *(const f2v*)&XFa[b][2 * lane];
        f2v xg = *(const f2v*)&XGa[b][2 * lane];
        float sp = wsum(pv[0] + pv[1]);
        float sf = wsum(pv[0] * xf[0] + pv[1] * xf[1]);
        float sg = wsum(pv[0] * xg[0] + pv[1] * xg[1]);
        float inv = rcp_f(sp);
        float ytc = sf * inv;
        ytg_ref   = sg * inv;
        // gate finish + LSTM update
        float g  = gdot + fmaf(wihv, ytc + y_s[b][s], bgv);
        float gb = dpp_mov<0xB1>(g);    // at quad lane 0: g=i, gb=f, gc=g, gd=o
        float gc = dpp_mov<0x4E>(g);
        float gd = dpp_mov<0x4E>(gb);
        if ((tid & 3) == 0) {
            float co = c32[b][cur][jD];
            float cn = sig_f(gb) * co + sig_f(g) * tanh_f(gc);
            float hn = sig_f(gd) * tanh_f(cn);
            c32[b][cur ^ 1][jD] = cn;
            h32[b][jD] = hn;
            float hp = __shfl_xor(hn, 4);
            float cp = __shfl_xor(cn, 4);
            if ((tid & 7) == 0) {
                int m0 = tid >> 3;
                int sl = m0 + 4 * (m0 >> 5);
                st2[b][cur ^ 1][sl]      = pkh2(hn, hp);
                st2[b][cur ^ 1][72 + sl] = pkh2(cn, cp);
            }
        }
    };

    // ================= staggered scan: 3 regions advance BOTH batches 1 step ===
    PH_A(0, 0);
    __syncthreads();
    PH_B(0);  PH_A(1, 0);
    __syncthreads();

    for (int s = 0; s < STEPS - 1; ++s) {
        PH_C(0, s, ytg0);      PH_B(1);
        __syncthreads();
        PH_A(0, s + 1);        PH_C(1, s, ytg1);
        __syncthreads();
        PH_B(0);               PH_A(1, s + 1);
        __syncthreads();
    }
    PH_C(0, STEPS - 1, ytg0);  PH_B(1);
    __syncthreads();
    PH_C(1, STEPS - 1, ytg1);
    __syncthreads();

    // ---- out = h·Wff[0:128] + β_last·XG + bff, per batch ----
    if (tid < 64) {
        float v0 = h32[0][lane] * Wff[lane] + h32[0][lane + 64] * Wff[lane + 64];
        v0 = wsum(v0);
        float v1 = h32[1][lane] * Wff[lane] + h32[1][lane + 64] * Wff[lane + 64];
        v1 = wsum(v1);
        if (lane == 0) {
            out[blockIdx.x * NB + 0] = v0 + ytg0 + bff[0];
            out[blockIdx.x * NB + 1] = v1 + ytg1 + bff[0];
        }
    }
}

extern "C" void kernel_launch(void* const* d_in, const int* in_sizes, int n_in,
                              void* d_out, int out_size, void* d_ws, size_t ws_size,
                              hipStream_t stream) {
    dec_kernel<<<Bsz / NB, NTH, 0, stream>>>(
        (const float*)d_in[0],  (const float*)d_in[1],  (const float*)d_in[2],
        (const float*)d_in[3],  (const float*)d_in[4],  (const float*)d_in[5],
        (const float*)d_in[6],  (const float*)d_in[7],  (const float*)d_in[8],
        (const float*)d_in[9],  (const float*)d_in[10], (const float*)d_in[11],
        (const float*)d_in[12], (const float*)d_in[13], (float*)d_out);
}